// Round 9
// baseline (314.239 us; speedup 1.0000x reference)
//
#include <hip/hip_runtime.h>
#include <hip/hip_cooperative_groups.h>
#include <stdint.h>

namespace cg = cooperative_groups;

#define NB 8
#define NS 256
#define ND 1024
#define EPSF 1e-5f
#define BIGF 3.0e38f

typedef __attribute__((ext_vector_type(8))) short short8;
typedef __attribute__((ext_vector_type(4))) float f32x4;

__device__ __forceinline__ unsigned short f2bf(float f) {
  unsigned int u = __float_as_uint(f);
  u = (u + 0x7FFFu + ((u >> 16) & 1u)) >> 16;
  return (unsigned short)u;
}

// Single cooperative kernel; ALL phases grid-stride so any granted grid works.
__global__ __launch_bounds__(256, 4) void k_fused(
    const float* __restrict__ x, unsigned short* __restrict__ Xb,
    unsigned short* __restrict__ Yb, float* __restrict__ Cp,
    float* __restrict__ C, float* __restrict__ S2,
    float* __restrict__ DGa, float* __restrict__ IXa,
    float* __restrict__ out) {
  __shared__ union {
    struct { float xt[256][9]; float tot[8][33]; } p1;   // ypfx tile + chunk totals
    struct { float As[64][17]; float Bs[64][34]; } p4;   // trop staging
  } sm;
  __shared__ float red[4];
  cg::grid_group grid = cg::this_grid();

  const int blk = blockIdx.x;
  const int nblk = gridDim.x;
  const int tid = threadIdx.x;
  const int wv = tid >> 6;
  const int lane = tid & 63;
  const int nwave = nblk << 2;

  // ======== Phase 1a: fp32->bf16 convert + exact diag/inv_xnorm (1 row per block-iter) ========
  for (int row = blk; row < NB * NS; row += nblk) {
    float4 v = reinterpret_cast<const float4*>(x + (size_t)row * ND)[tid];
    ushort4 ob;
    ob.x = f2bf(v.x); ob.y = f2bf(v.y); ob.z = f2bf(v.z); ob.w = f2bf(v.w);
    reinterpret_cast<ushort4*>(Xb + (size_t)row * ND)[tid] = ob;
    float sq = v.x * v.x + v.y * v.y + v.z * v.z + v.w * v.w;
#pragma unroll
    for (int off = 32; off; off >>= 1) sq += __shfl_xor(sq, off);
    if (lane == 0) red[wv] = sq;
    __syncthreads();
    if (tid == 0) {
      float s = red[0] + red[1] + red[2] + red[3];
      DGa[row] = s;
      IXa[row] = 1.0f / sqrtf(s);   // inf if 0 -> forces slow path
    }
    __syncthreads();
  }

  // ======== Phase 1b: Y column prefix, LDS-transposed (8-col tile per block-iter) ========
  for (int tile = blk; tile < 1024; tile += nblk) {
    __syncthreads();                  // protect LDS reuse across iterations/phases
    int b = tile >> 7;
    int d0 = (tile & 127) << 3;
    const float* xs = x + ((size_t)b << 18) + d0;
#pragma unroll
    for (int q = 0; q < 2; ++q) {
      int slot = tid + (q << 8);
      int s = slot >> 1, h = (slot & 1) << 2;
      float4 v = *reinterpret_cast<const float4*>(xs + (size_t)s * ND + h);
      sm.p1.xt[s][h + 0] = v.x;
      sm.p1.xt[s][h + 1] = v.y;
      sm.p1.xt[s][h + 2] = v.z;
      sm.p1.xt[s][h + 3] = v.w;
    }
    __syncthreads();
    int col = tid & 7, ch = tid >> 3;   // 32 chunks x 8 rows
    float loc[8];
    float run = 0.f;
#pragma unroll
    for (int r = 0; r < 8; ++r) { run += sm.p1.xt[ch * 8 + r][col]; loc[r] = run; }
    sm.p1.tot[col][ch] = run;
    __syncthreads();
#pragma unroll
    for (int off = 1; off < 32; off <<= 1) {
      float tv = (ch >= off) ? sm.p1.tot[col][ch - off] : 0.f;
      __syncthreads();
      sm.p1.tot[col][ch] += tv;
      __syncthreads();
    }
    float excl = sm.p1.tot[col][ch] - run;
#pragma unroll
    for (int r = 0; r < 8; ++r) sm.p1.xt[ch * 8 + r][col] = excl + loc[r];
    __syncthreads();
    unsigned short* yr = Yb + ((size_t)b << 18) + (size_t)tid * ND + d0;
    ushort4 o0, o1;
    o0.x = f2bf(sm.p1.xt[tid][0]); o0.y = f2bf(sm.p1.xt[tid][1]);
    o0.z = f2bf(sm.p1.xt[tid][2]); o0.w = f2bf(sm.p1.xt[tid][3]);
    o1.x = f2bf(sm.p1.xt[tid][4]); o1.y = f2bf(sm.p1.xt[tid][5]);
    o1.z = f2bf(sm.p1.xt[tid][6]); o1.w = f2bf(sm.p1.xt[tid][7]);
    reinterpret_cast<ushort4*>(yr)[0] = o0;
    reinterpret_cast<ushort4*>(yr)[1] = o1;
  }

  grid.sync();

  // ======== Phase 2: C partials (4096 16x16 K-split-2 wave jobs, grid-stride) ========
  for (int job = (blk << 2) + wv; job < 4096; job += nwave) {
    int b = job >> 9;
    int r2 = job & 511;
    int ks = r2 & 1;
    int nt = (r2 >> 1) & 15;
    int mt = r2 >> 5;
    const unsigned short* Ab = Yb + ((size_t)b << 18) + ((size_t)(mt << 4) << 10);
    const unsigned short* Bb = Xb + ((size_t)b << 18) + ((size_t)(nt << 4) << 10);
    int lr = lane & 15;
    int kbase = (ks << 9) + ((lane >> 4) << 3);
    f32x4 ae = {0.f, 0.f, 0.f, 0.f}, ao = {0.f, 0.f, 0.f, 0.f};
#pragma unroll 4
    for (int kk = 0; kk < 512; kk += 64) {
      const unsigned short* ap = Ab + ((size_t)lr << 10) + kbase + kk;
      const unsigned short* bp = Bb + ((size_t)lr << 10) + kbase + kk;
      short8 a0 = *reinterpret_cast<const short8*>(ap);
      short8 b0 = *reinterpret_cast<const short8*>(bp);
      short8 a1 = *reinterpret_cast<const short8*>(ap + 32);
      short8 b1 = *reinterpret_cast<const short8*>(bp + 32);
      ae = __builtin_amdgcn_mfma_f32_16x16x32_bf16(a0, b0, ae, 0, 0, 0);
      ao = __builtin_amdgcn_mfma_f32_16x16x32_bf16(a1, b1, ao, 0, 0, 0);
    }
    f32x4 acc = ae + ao;
    // C/D layout: col = lane&15, row = (lane>>4)*4 + j   [measured m89]
    float* P = Cp + (size_t)ks * (NB * NS * NS) + ((size_t)b << 16);
    int r0 = (mt << 4) + ((lane >> 4) << 2);
    int c0 = (nt << 4) + lr;
#pragma unroll
    for (int j = 0; j < 4; ++j) P[(size_t)(r0 + j) * NS + c0] = acc[j];
  }

  grid.sync();

  // ======== Phase 3: reduce partials -> C rows (row 0 = 0) + S2 row prefix ========
  for (int job = (blk << 2) + wv; job < NB * 257; job += nwave) {
    int b = job / 257;
    int r = job - b * 257;
    float* Crow = C + ((size_t)b * 257 + r) * NS;
    float* Srow = S2 + ((size_t)b * 257 + r) * 257;
    int rm1 = (r > 0) ? (r - 1) : 0;
    const float* p0 = Cp + (((size_t)b << 8) + rm1) * NS;
    const float* p1 = p0 + (size_t)(NB * NS * NS);
    if (lane == 0) Srow[0] = 0.f;
    float run = 0.f;
    for (int c0 = 0; c0 < NS; c0 += 64) {
      float v = 0.f;
      if (r > 0) v = p0[c0 + lane] + p1[c0 + lane];
      Crow[c0 + lane] = v;
#pragma unroll
      for (int off = 1; off < 64; off <<= 1) {
        float n = __shfl_up(v, off);
        if (lane >= off) v += n;
      }
      Srow[c0 + lane + 1] = run + v;
      run += __shfl(v, 63);
    }
  }

  grid.sync();

  // ======== Phase 4: tropical min + epilogue (16x32 tile per block-iter) ========
  for (int tile = blk; tile < 1024; tile += nblk) {
    __syncthreads();                  // protect LDS (As/Bs/red) reuse across iterations
    int b = tile >> 7;
    int tix = tile & 127;
    int i0 = (tix >> 3) << 4;
    int j0 = (tix & 7) << 5;
    float* outb = out + ((size_t)b << 16);

    if (i0 > j0 + 30) {               // no valid (i,j) in tile: zero-fill
      float2 z = {0.f, 0.f};
      *reinterpret_cast<float2*>(outb + (size_t)(i0 + (tid >> 4)) * NS + j0 + ((tid & 15) << 1)) = z;
      continue;
    }

    const float* Cb = C + (size_t)b * 257 * NS;
    const float* IXb = IXa + b * NS;
    float w0 = IXb[tid];
#pragma unroll
    for (int off = 32; off; off >>= 1) w0 = fmaxf(w0, __shfl_xor(w0, off));
    if (lane == 0) red[wv] = w0;
    __syncthreads();
    float wmb = fmaxf(fmaxf(red[0], red[1]), fmaxf(red[2], red[3]));

    int ii = tid >> 4;                // 0..15
    int jj = (tid & 15) << 1;         // 0,2,..,30
    float acc0 = BIGF, acc1 = BIGF;

    for (int t0 = i0 & ~63; t0 < j0 + 32; t0 += 64) {
      __syncthreads();
#pragma unroll
      for (int q = 0; q < 3; ++q) {   // stage 48 C-rows * 64 t, scaled by inv_xnorm
        int slot = tid + (q << 8);
        int rrow = slot >> 4;
        int c4 = (slot & 15) << 2;
        float4 wv4 = *reinterpret_cast<const float4*>(IXb + t0 + c4);
        if (rrow < 16) {
          float4 v = *reinterpret_cast<const float4*>(Cb + (size_t)(i0 + rrow) * NS + t0 + c4);
          sm.p4.As[c4 + 0][rrow] = v.x * wv4.x;
          sm.p4.As[c4 + 1][rrow] = v.y * wv4.y;
          sm.p4.As[c4 + 2][rrow] = v.z * wv4.z;
          sm.p4.As[c4 + 3][rrow] = v.w * wv4.w;
        } else {
          int rb = rrow - 16;
          float4 v = *reinterpret_cast<const float4*>(Cb + (size_t)(j0 + 1 + rb) * NS + t0 + c4);
          sm.p4.Bs[c4 + 0][rb] = v.x * wv4.x;
          sm.p4.Bs[c4 + 1][rb] = v.y * wv4.y;
          sm.p4.Bs[c4 + 2][rb] = v.z * wv4.z;
          sm.p4.Bs[c4 + 3][rb] = v.w * wv4.w;
        }
      }
      __syncthreads();
      int thA = i0 + ii - t0;         // a valid iff tt >= thA
      int thB = j0 + jj - t0;         // b_l valid iff tt <= thB + l
      if (thA <= 0 && thB >= 63) {
#pragma unroll 8
        for (int tt = 0; tt < 64; ++tt) {
          float a = sm.p4.As[tt][ii];
          float2 bv = *reinterpret_cast<const float2*>(&sm.p4.Bs[tt][jj]);
          acc0 = fminf(acc0, bv.x - a);
          acc1 = fminf(acc1, bv.y - a);
        }
      } else {
#pragma unroll 8
        for (int tt = 0; tt < 64; ++tt) {
          float a = (tt >= thA) ? sm.p4.As[tt][ii] : -BIGF;
          float2 bv = *reinterpret_cast<const float2*>(&sm.p4.Bs[tt][jj]);
          float b0 = (tt <= thB) ? bv.x : BIGF;
          float b1 = (tt <= thB + 1) ? bv.y : BIGF;
          acc0 = fminf(acc0, b0 - a);
          acc1 = fminf(acc1, b1 - a);
        }
      }
    }

    const float* S2b = S2 + (size_t)b * 257 * 257;
    const float* DGb = DGa + b * NS;
    int i = i0 + ii;
    float res[2] = {0.f, 0.f};
    if (i >= 1) {
      float s2ii = S2b[(size_t)i * 257 + i];
      float am[2] = {acc0, acc1};
#pragma unroll
      for (int l = 0; l < 2; ++l) {
        int j = j0 + jj + l;
        if (j > i) {
          float s2jj = S2b[(size_t)(j + 1) * 257 + (j + 1)];
          float s2ij = S2b[(size_t)i * 257 + (j + 1)];
          float s2ji = S2b[(size_t)(j + 1) * 257 + i];
          float ssq = (s2jj - s2ij) - (s2ji - s2ii);
          float sn = sqrtf(fmaxf(ssq, 0.f));
          float win = (float)(j - i + 1);
          if (sn >= EPSF * win * wmb) {
            res[l] = am[l] / sn;      // fast path: EPS never binds
          } else {
            float mn = sn / win;
            float m = BIGF;
            const float* r2p = Cb + (size_t)(j + 1) * NS;
            const float* r1p = Cb + (size_t)i * NS;
            for (int t = i; t <= j; ++t) {
              float num = r2p[t] - r1p[t];
              float xn = sqrtf(fmaxf(DGb[t], 0.f));
              float den = fmaxf(mn * xn, EPSF);
              m = fminf(m, num / win / den);
            }
            res[l] = m;
          }
        }
      }
    }
    float2 st = {res[0], res[1]};
    *reinterpret_cast<float2*>(outb + (size_t)i * NS + j0 + jj) = st;
  }
}

extern "C" void kernel_launch(void* const* d_in, const int* in_sizes, int n_in,
                              void* d_out, int out_size, void* d_ws, size_t ws_size,
                              hipStream_t stream) {
  (void)in_sizes; (void)n_in; (void)ws_size; (void)out_size;
  const float* x = (const float*)d_in[0];
  float* out = (float*)d_out;
  char* ws = (char*)d_ws;
  unsigned short* Xb = (unsigned short*)(ws);                 //  4,194,304 B
  unsigned short* Yb = (unsigned short*)(ws + 4194304);       //  4,194,304 B
  float* Cp  = (float*)(ws + 8388608);                        //  4,194,304 B (2 x 8 x 256 x 256)
  float* C   = (float*)(ws + 12582912);                       //  2,105,344 B (8 x 257 x 256)
  float* S2  = (float*)(ws + 14688256);                       //  2,113,568 B (8 x 257 x 257)
  float* DGa = (float*)(ws + 16801824);                       //  8,192 B
  float* IXa = (float*)(ws + 16810016);                       //  8,192 B

  // Query the cooperative co-residency cap (pure query: graph-capture safe,
  // deterministic every call). R8 failure: blind 1024-block coop launch was
  // rejected by the driver -> kernel never ran.
  int maxB = 0;
  if (hipOccupancyMaxActiveBlocksPerMultiprocessor(&maxB, k_fused, 256, 0) != hipSuccess || maxB < 1)
    maxB = 1;                       // 256-block coop launch proven to work (R5)
  long grid = (long)maxB * 256;
  if (grid > 1024) grid = 1024;

  void* args[] = {(void*)&x, (void*)&Xb, (void*)&Yb, (void*)&Cp, (void*)&C,
                  (void*)&S2, (void*)&DGa, (void*)&IXa, (void*)&out};
  hipLaunchCooperativeKernel((void*)k_fused, dim3((uint32_t)grid), dim3(256), args, 0, stream);
}

// Round 10
// 109.143 us; speedup vs baseline: 2.8791x; 2.8791x over previous
//
#include <hip/hip_runtime.h>
#include <stdint.h>

#define NB 8
#define NS 256
#define ND 1024
#define EPSF 1e-5f
#define BIGF 3.0e38f

typedef __attribute__((ext_vector_type(8))) short short8;
typedef __attribute__((ext_vector_type(4))) float f32x4;

__device__ __forceinline__ unsigned short f2bf(float f) {
  unsigned int u = __float_as_uint(f);
  u = (u + 0x7FFFu + ((u >> 16) & 1u)) >> 16;
  return (unsigned short)u;
}

// ---- k_pre: role A (blk<512) convert+diag; role B (512..1535) LDS-transposed ypfx ----
__global__ __launch_bounds__(256) void k_pre(const float* __restrict__ x,
                                             unsigned short* __restrict__ Xb,
                                             unsigned short* __restrict__ Yb,
                                             float* __restrict__ DGa,
                                             float* __restrict__ IXa) {
  __shared__ struct { float xt[256][9]; float tot[8][33]; } sm;
  int blk = blockIdx.x;
  int tid = threadIdx.x;
  int lane = tid & 63;

  if (blk < 512) {
    // convert: 4 rows/block (one per wave), coalesced float4
    int row = blk * 4 + (tid >> 6);
    size_t base = (size_t)row * ND;
    float sq = 0.f;
#pragma unroll
    for (int c = 0; c < 4; ++c) {
      size_t o = base + c * 256 + lane * 4;
      float4 v = *reinterpret_cast<const float4*>(x + o);
      ushort4 ob;
      ob.x = f2bf(v.x); ob.y = f2bf(v.y); ob.z = f2bf(v.z); ob.w = f2bf(v.w);
      *reinterpret_cast<ushort4*>(Xb + o) = ob;
      sq += v.x * v.x + v.y * v.y + v.z * v.z + v.w * v.w;
    }
#pragma unroll
    for (int off = 32; off; off >>= 1) sq += __shfl_xor(sq, off);
    if (lane == 0) {
      DGa[row] = sq;
      IXa[row] = 1.0f / sqrtf(sq);   // inf if 0 -> forces slow path
    }
    return;
  }

  // ypfx: inclusive prefix along s for an 8-column tile, via LDS transpose
  int tile = blk - 512;                // 0..1023
  int b = tile >> 7;
  int d0 = (tile & 127) << 3;
  const float* xs = x + ((size_t)b << 18) + d0;
#pragma unroll
  for (int q = 0; q < 2; ++q) {
    int slot = tid + (q << 8);
    int s = slot >> 1, h = (slot & 1) << 2;
    float4 v = *reinterpret_cast<const float4*>(xs + (size_t)s * ND + h);
    sm.xt[s][h + 0] = v.x;
    sm.xt[s][h + 1] = v.y;
    sm.xt[s][h + 2] = v.z;
    sm.xt[s][h + 3] = v.w;
  }
  __syncthreads();
  int col = tid & 7, ch = tid >> 3;    // 32 chunks x 8 rows each
  float loc[8];
  float run = 0.f;
#pragma unroll
  for (int r = 0; r < 8; ++r) { run += sm.xt[ch * 8 + r][col]; loc[r] = run; }
  sm.tot[col][ch] = run;
  __syncthreads();
#pragma unroll
  for (int off = 1; off < 32; off <<= 1) {
    float tv = (ch >= off) ? sm.tot[col][ch - off] : 0.f;
    __syncthreads();
    sm.tot[col][ch] += tv;
    __syncthreads();
  }
  float excl = sm.tot[col][ch] - run;
#pragma unroll
  for (int r = 0; r < 8; ++r) sm.xt[ch * 8 + r][col] = excl + loc[r];
  __syncthreads();
  unsigned short* yr = Yb + ((size_t)b << 18) + (size_t)tid * ND + d0;
  ushort4 o0, o1;
  o0.x = f2bf(sm.xt[tid][0]); o0.y = f2bf(sm.xt[tid][1]);
  o0.z = f2bf(sm.xt[tid][2]); o0.w = f2bf(sm.xt[tid][3]);
  o1.x = f2bf(sm.xt[tid][4]); o1.y = f2bf(sm.xt[tid][5]);
  o1.z = f2bf(sm.xt[tid][6]); o1.w = f2bf(sm.xt[tid][7]);
  reinterpret_cast<ushort4*>(yr)[0] = o0;
  reinterpret_cast<ushort4*>(yr)[1] = o1;
}

// ---- k_gemmC: C[1+rr, t] = Y_rr . x_t, 2048 16x16 K=1024 wave jobs, direct C write ----
__global__ __launch_bounds__(256) void k_gemmC(const unsigned short* __restrict__ yb,
                                               const unsigned short* __restrict__ xb,
                                               float* __restrict__ C) {
  int job = (blockIdx.x << 2) + (threadIdx.x >> 6);   // 0..2047
  int lane = threadIdx.x & 63;
  int b = job >> 8;
  int mt = (job >> 4) & 15;
  int nt = job & 15;
  const unsigned short* Ab = yb + ((size_t)b << 18) + ((size_t)(mt << 4) << 10);
  const unsigned short* Bb = xb + ((size_t)b << 18) + ((size_t)(nt << 4) << 10);
  int lr = lane & 15;
  int kbase = (lane >> 4) << 3;
  f32x4 ae = {0.f, 0.f, 0.f, 0.f}, ao = {0.f, 0.f, 0.f, 0.f};
#pragma unroll 4
  for (int kk = 0; kk < 1024; kk += 64) {
    const unsigned short* ap = Ab + ((size_t)lr << 10) + kbase + kk;
    const unsigned short* bp = Bb + ((size_t)lr << 10) + kbase + kk;
    short8 a0 = *reinterpret_cast<const short8*>(ap);
    short8 b0 = *reinterpret_cast<const short8*>(bp);
    short8 a1 = *reinterpret_cast<const short8*>(ap + 32);
    short8 b1 = *reinterpret_cast<const short8*>(bp + 32);
    ae = __builtin_amdgcn_mfma_f32_16x16x32_bf16(a0, b0, ae, 0, 0, 0);
    ao = __builtin_amdgcn_mfma_f32_16x16x32_bf16(a1, b1, ao, 0, 0, 0);
  }
  f32x4 acc = ae + ao;
  // C/D layout: col = lane&15, row = (lane>>4)*4 + j   [measured m89]
  float* Cb = C + (size_t)b * 257 * NS;
  int r0 = (mt << 4) + ((lane >> 4) << 2) + 1;   // C row = tile row + 1
  int c0 = (nt << 4) + lr;
#pragma unroll
  for (int j = 0; j < 4; ++j) Cb[(size_t)(r0 + j) * NS + c0] = acc[j];
}

// ---- k_scan: C row 0 := 0; S2[r,c] = prefix of C row r ----
__global__ __launch_bounds__(256) void k_scan(float* __restrict__ C, float* __restrict__ S2) {
  int id = blockIdx.x * 4 + (threadIdx.x >> 6);   // 0..2055
  int lane = threadIdx.x & 63;
  int b = id / 257;
  int r = id - b * 257;
  float* Crow = C + ((size_t)b * 257 + r) * NS;
  float* Srow = S2 + ((size_t)b * 257 + r) * 257;
  if (lane == 0) Srow[0] = 0.f;
  float run = 0.f;
  for (int c0 = 0; c0 < NS; c0 += 64) {
    float v;
    if (r > 0) {
      v = Crow[c0 + lane];
    } else {
      v = 0.f;
      Crow[c0 + lane] = 0.f;          // zero C row 0 (read by k_trop)
    }
#pragma unroll
    for (int off = 1; off < 64; off <<= 1) {
      float n = __shfl_up(v, off);
      if (lane >= off) v += n;
    }
    Srow[c0 + lane + 1] = run + v;
    run += __shfl(v, 63);
  }
}

// ---- k_trop: worst[i,j] = min_t (W[j+1,t]-W[i,t]) / sn(i,j)  (R4-proven body) ----
__global__ __launch_bounds__(256) void k_trop(const float* __restrict__ C,
                                              const float* __restrict__ S2,
                                              const float* __restrict__ IXa,
                                              const float* __restrict__ DGa,
                                              float* __restrict__ out) {
  __shared__ float As[64][36];   // As[tt][ii]
  __shared__ float Bs[64][68];   // Bs[tt][jj]
  __shared__ float wred[4];
  int blk = blockIdx.x;
  int b = blk >> 5;
  int tix = blk & 31;
  int i0 = (tix >> 2) << 5;
  int j0 = (tix & 3) << 6;
  int tid = threadIdx.x;
  float* outb = out + ((size_t)b << 16);

  if (i0 >= j0 + 63) {           // fully-invalid tile: zero-fill
    float4 z = {0.f, 0.f, 0.f, 0.f};
    float* p = outb + (size_t)(i0 + (tid >> 3)) * NS + j0 + ((tid & 7) << 3);
    reinterpret_cast<float4*>(p)[0] = z;
    reinterpret_cast<float4*>(p)[1] = z;
    return;
  }

  const float* Cb = C + (size_t)b * 257 * NS;
  const float* IXb = IXa + b * NS;

  float wv0 = IXb[tid];
#pragma unroll
  for (int off = 32; off; off >>= 1) wv0 = fmaxf(wv0, __shfl_xor(wv0, off));
  if ((tid & 63) == 0) wred[tid >> 6] = wv0;
  __syncthreads();
  float wmb = fmaxf(fmaxf(wred[0], wred[1]), fmaxf(wred[2], wred[3]));

  int ii0 = (tid >> 4) << 1;     // 0,2,...,30
  int jj0 = (tid & 15) << 2;     // 0,4,...,60
  float acc[8];
#pragma unroll
  for (int k = 0; k < 8; ++k) acc[k] = BIGF;

  int rA = tid >> 4;             // 0..15
  int c4 = (tid & 15) << 2;      // 0..60

  for (int t0 = i0 & ~63; t0 < j0 + 64; t0 += 64) {
    __syncthreads();
    float4 wv = *reinterpret_cast<const float4*>(IXb + t0 + c4);
#pragma unroll
    for (int p = 0; p < 2; ++p) {      // A: rows i0..i0+31
      int r = i0 + p * 16 + rA;
      float4 v = *reinterpret_cast<const float4*>(Cb + (size_t)r * NS + t0 + c4);
      As[c4 + 0][p * 16 + rA] = v.x * wv.x;
      As[c4 + 1][p * 16 + rA] = v.y * wv.y;
      As[c4 + 2][p * 16 + rA] = v.z * wv.z;
      As[c4 + 3][p * 16 + rA] = v.w * wv.w;
    }
#pragma unroll
    for (int p = 0; p < 4; ++p) {      // B: rows j0+1..j0+64
      int r = j0 + 1 + p * 16 + rA;
      float4 v = *reinterpret_cast<const float4*>(Cb + (size_t)r * NS + t0 + c4);
      Bs[c4 + 0][p * 16 + rA] = v.x * wv.x;
      Bs[c4 + 1][p * 16 + rA] = v.y * wv.y;
      Bs[c4 + 2][p * 16 + rA] = v.z * wv.z;
      Bs[c4 + 3][p * 16 + rA] = v.w * wv.w;
    }
    __syncthreads();

    int thA = i0 + ii0 - t0;   // a[k] valid iff tt >= thA + k
    int thB = j0 + jj0 - t0;   // b[l] valid iff tt <= thB + l
    if (thA <= -1 && thB >= 63) {
#pragma unroll 4
      for (int tt = 0; tt < 64; ++tt) {
        float2 a = *reinterpret_cast<const float2*>(&As[tt][ii0]);
        float4 bv = *reinterpret_cast<const float4*>(&Bs[tt][jj0]);
        acc[0] = fminf(acc[0], bv.x - a.x);
        acc[1] = fminf(acc[1], bv.y - a.x);
        acc[2] = fminf(acc[2], bv.z - a.x);
        acc[3] = fminf(acc[3], bv.w - a.x);
        acc[4] = fminf(acc[4], bv.x - a.y);
        acc[5] = fminf(acc[5], bv.y - a.y);
        acc[6] = fminf(acc[6], bv.z - a.y);
        acc[7] = fminf(acc[7], bv.w - a.y);
      }
    } else {
#pragma unroll 4
      for (int tt = 0; tt < 64; ++tt) {
        float2 a = *reinterpret_cast<const float2*>(&As[tt][ii0]);
        float4 bv = *reinterpret_cast<const float4*>(&Bs[tt][jj0]);
        float a0 = (tt >= thA)     ? a.x  : -BIGF;
        float a1 = (tt >= thA + 1) ? a.y  : -BIGF;
        float b0 = (tt <= thB)     ? bv.x :  BIGF;
        float b1 = (tt <= thB + 1) ? bv.y :  BIGF;
        float b2 = (tt <= thB + 2) ? bv.z :  BIGF;
        float b3 = (tt <= thB + 3) ? bv.w :  BIGF;
        acc[0] = fminf(acc[0], b0 - a0);
        acc[1] = fminf(acc[1], b1 - a0);
        acc[2] = fminf(acc[2], b2 - a0);
        acc[3] = fminf(acc[3], b3 - a0);
        acc[4] = fminf(acc[4], b0 - a1);
        acc[5] = fminf(acc[5], b1 - a1);
        acc[6] = fminf(acc[6], b2 - a1);
        acc[7] = fminf(acc[7], b3 - a1);
      }
    }
  }

  const float* S2b = S2 + (size_t)b * 257 * 257;
  const float* DGb = DGa + b * NS;
#pragma unroll
  for (int k = 0; k < 2; ++k) {
    int i = i0 + ii0 + k;
    float o4[4];
    float s2ii = S2b[(size_t)i * 257 + i];
#pragma unroll
    for (int l = 0; l < 4; ++l) {
      int j = j0 + jj0 + l;
      float res = 0.f;
      if (i >= 1 && j > i) {
        float s2jj = S2b[(size_t)(j + 1) * 257 + (j + 1)];
        float s2ij = S2b[(size_t)i * 257 + (j + 1)];
        float s2ji = S2b[(size_t)(j + 1) * 257 + i];
        float ssq = (s2jj - s2ij) - (s2ji - s2ii);
        float sn = sqrtf(fmaxf(ssq, 0.f));
        float win = (float)(j - i + 1);
        if (sn >= EPSF * win * wmb) {
          res = acc[k * 4 + l] / sn;               // fast path: EPS never binds
        } else {
          float mn = sn / win;
          float m = BIGF;
          const float* r2 = Cb + (size_t)(j + 1) * NS;
          const float* r1 = Cb + (size_t)i * NS;
          for (int t = i; t <= j; ++t) {
            float num = r2[t] - r1[t];
            float xn = sqrtf(fmaxf(DGb[t], 0.f));
            float den = fmaxf(mn * xn, EPSF);
            m = fminf(m, num / win / den);
          }
          res = m;
        }
      }
      o4[l] = res;
    }
    float4 st = {o4[0], o4[1], o4[2], o4[3]};
    *reinterpret_cast<float4*>(outb + (size_t)i * NS + j0 + jj0) = st;
  }
}

extern "C" void kernel_launch(void* const* d_in, const int* in_sizes, int n_in,
                              void* d_out, int out_size, void* d_ws, size_t ws_size,
                              hipStream_t stream) {
  (void)in_sizes; (void)n_in; (void)ws_size; (void)out_size;
  const float* x = (const float*)d_in[0];
  float* out = (float*)d_out;
  char* ws = (char*)d_ws;
  unsigned short* Xb = (unsigned short*)(ws);                 //  4,194,304 B
  unsigned short* Yb = (unsigned short*)(ws + 4194304);       //  4,194,304 B
  float* C   = (float*)(ws + 8388608);                        //  2,105,344 B (8 x 257 x 256)
  float* S2  = (float*)(ws + 10493952);                       //  2,113,568 B (8 x 257 x 257)
  float* DGa = (float*)(ws + 12607520);                       //  8,192 B
  float* IXa = (float*)(ws + 12615712);                       //  8,192 B

  k_pre<<<1536, 256, 0, stream>>>(x, Xb, Yb, DGa, IXa);
  k_gemmC<<<512, 256, 0, stream>>>(Yb, Xb, C);
  k_scan<<<514, 256, 0, stream>>>(C, S2);
  k_trop<<<256, 256, 0, stream>>>(C, S2, IXa, DGa, out);
}